// Round 19
// baseline (526.222 us; speedup 1.0000x reference)
//
#include <hip/hip_runtime.h>
#include <hip/hip_bf16.h>
#include <math.h>

// Problem constants
#define N_TRAIN 4096
#define N_FEAT  64
#define NHID    256
#define ENC     256
#define GH      256
#define AH      64
#define NANTES  32768
#define TSTEPS  32

#define SSTR 528   // lstm setup LDS row stride (f32)

typedef __attribute__((ext_vector_type(8))) short bf16x8;
typedef __attribute__((ext_vector_type(4))) float f32x4;

#define BMFMA(a_, b_, c_) __builtin_amdgcn_mfma_f32_16x16x32_bf16(a_, b_, c_, 0, 0, 0)

__device__ __forceinline__ float sigmoidf_(float x) {
    return 1.0f / (1.0f + __expf(-x));
}
__device__ __forceinline__ float tanhf_(float x) {
    return 1.0f - 2.0f / (__expf(2.0f * x) + 1.0f);
}
__device__ __forceinline__ unsigned short f2bf_rne(float x) {
    unsigned int u = __float_as_uint(x);
    unsigned int r = u + 0x7FFFu + ((u >> 16) & 1u);
    return (unsigned short)(r >> 16);
}
__device__ __forceinline__ float bf2f(unsigned short b) {
    return __uint_as_float(((unsigned int)b) << 16);
}

// async 16B/lane global -> LDS (wave-uniform LDS base, per-lane global src)
__device__ __forceinline__ void async16(const void* g, void* l) {
    __builtin_amdgcn_global_load_lds(
        (const __attribute__((address_space(1))) void*)g,
        (__attribute__((address_space(3))) void*)l, 16, 0, 0);
}

// ---------------------------------------------------------------------------
// Kernel PREP (fused): zero esum + pack Whh and Wih (bf16 hi, fragment
// order; both are [1024][256] row-major) + pack attW1[:4096] (bf16 hi/lo,
// B-fragment order). Grid 128 x 256.
// ---------------------------------------------------------------------------
__global__ void prep_kernel(const float* __restrict__ Whh,
                            unsigned short* __restrict__ Wph,
                            const float* __restrict__ Wih,
                            unsigned short* __restrict__ Wpi,
                            const float* __restrict__ attW1,
                            unsigned short* __restrict__ Wah,
                            unsigned short* __restrict__ Wal,
                            float* __restrict__ esum)
{
    int g = blockIdx.x * 256 + threadIdx.x;      // 0 .. 32767
    if (g < TSTEPS * GH) esum[g] = 0.0f;

    {   // pack Whh + Wih: group g = ((ntile*8 + ks)*64 + lane)
        int lane  = g & 63;
        int ks    = (g >> 6) & 7;
        int ntile = g >> 9;
        int n  = ntile * 16 + (lane & 15);
        int k0 = ks * 32 + (lane >> 4) * 8;
        const float* src1 = Whh + n * 256 + k0;
        const float* src2 = Wih + n * 256 + k0;
        #pragma unroll
        for (int jj = 0; jj < 8; ++jj) {
            Wph[g * 8 + jj] = f2bf_rne(src1[jj]);
            Wpi[g * 8 + jj] = f2bf_rne(src2[jj]);
        }
    }
    {   // pack_wa: group g = ((ct*128 + ks)*64 + lane)
        int lane = g & 63;
        int ks   = (g >> 6) & 127;
        int ct   = g >> 13;
        int n  = ct * 16 + (lane & 15);
        int k0 = ks * 32 + (lane >> 4) * 8;
        const float* src = attW1 + (size_t)k0 * AH + n;
        #pragma unroll
        for (int jj = 0; jj < 8; ++jj) {
            float x = src[(size_t)jj * AH];
            unsigned short h16 = f2bf_rne(x);
            Wah[g * 8 + jj] = h16;
            Wal[g * 8 + jj] = f2bf_rne(x - bf2f(h16));
        }
    }
}

// ---------------------------------------------------------------------------
// Kernel A: fused encoder -> MFMA x_proj -> 32-step MFMA LSTM -> h sums
// (unchanged from round 18 — best measured configuration)
// ---------------------------------------------------------------------------
__global__ __launch_bounds__(512, 2) void lstm_kernel(
    const float* __restrict__ ctx,
    const float* __restrict__ encW1, const float* __restrict__ encb1,
    const float* __restrict__ encW2, const float* __restrict__ encb2,
    const float* __restrict__ bih,  const float* __restrict__ bhh,
    const unsigned short* __restrict__ Wph,
    const unsigned short* __restrict__ Wpi,
    float* __restrict__ esum)
{
    __shared__ char pool[98304];           // B ring (8 waves x 3 x 4KB); sbuf aliased
    __shared__ short hhi[2][16 * 256];     // 8 KB x2, XOR-swizzled cols
    __shared__ short hlo[2][16 * 256];

    float* sbuf = (float*)pool;            // setup scratch (33792 B <= ring)

    const int tid   = threadIdx.x;
    const int j     = tid & 255;
    const int rh    = tid >> 8;
    const int rbase = rh * 8;
    const int r0    = blockIdx.x * 16;

    const int w    = tid >> 6;        // wave 0..7
    const int l    = tid & 63;
    const int col  = l & 15;          // C col / A row
    const int kp   = l >> 4;          // 0..3
    const int arow = col;
    const int asw  = (arow & 7) << 3; // short-unit XOR swizzle

    // ==================== setup ====================
    {
        float acc[8];
        float b = encb1[j];
        #pragma unroll
        for (int r = 0; r < 8; ++r) acc[r] = b;
        for (int k = 0; k < N_FEAT; ++k) {
            float wv = encW1[k * NHID + j];
            #pragma unroll
            for (int r = 0; r < 8; ++r)
                acc[r] = fmaf(ctx[(r0 + rbase + r) * N_FEAT + k], wv, acc[r]);
        }
        #pragma unroll
        for (int r = 0; r < 8; ++r)
            sbuf[(rbase + r) * SSTR + j] = fmaxf(acc[r], 0.0f);
    }
    __syncthreads();

    // phi = hid @ encW2 + b2 (f32x4 LDS reads), staged hi/lo -> hhi[1]/hlo[1]
    {
        float p[8];
        float b = encb2[j];
        #pragma unroll
        for (int r = 0; r < 8; ++r) p[r] = b;
        for (int k4 = 0; k4 < NHID / 4; ++k4) {
            float w0 = encW2[(k4 * 4 + 0) * ENC + j];
            float w1 = encW2[(k4 * 4 + 1) * ENC + j];
            float w2 = encW2[(k4 * 4 + 2) * ENC + j];
            float w3 = encW2[(k4 * 4 + 3) * ENC + j];
            #pragma unroll
            for (int r = 0; r < 8; ++r) {
                const f32x4 hv = *(const f32x4*)&sbuf[(rbase + r) * SSTR + k4 * 4];
                float v = p[r];
                v = fmaf(hv[0], w0, v);
                v = fmaf(hv[1], w1, v);
                v = fmaf(hv[2], w2, v);
                v = fmaf(hv[3], w3, v);
                p[r] = v;
            }
        }
        #pragma unroll
        for (int r = 0; r < 8; ++r) {
            int row = rbase + r;
            unsigned short h16 = f2bf_rne(p[r]);
            float lof = p[r] - bf2f(h16);
            int sidx = row * 256 + (j ^ ((row & 7) << 3));
            hhi[1][sidx] = (short)h16;
            hlo[1][sidx] = (short)f2bf_rne(lof);
        }
    }
    // zero h buffer 0 (t=0 A-operand)
    for (int i = tid; i < 16 * 256; i += 512) { hhi[0][i] = 0; hlo[0][i] = 0; }
    __syncthreads();   // phi staged + zeros visible to all waves

    // ---- x_proj MFMA prologue: xpf = bias + phi @ Wih^T ----
    f32x4 xpf[4][2];
    #pragma unroll
    for (int g = 0; g < 4; ++g)
        #pragma unroll
        for (int u = 0; u < 2; ++u) {
            int m = g * 256 + w * 32 + u * 16 + col;
            float b = bih[m] + bhh[m];
            xpf[g][u] = (f32x4){b, b, b, b};
        }

    const unsigned short* Wi2 = Wpi + (size_t)l * 8 + (size_t)w * 8192;

#define XLOAD(dst, gj) do {                                                  \
        const int u_ = (gj) >> 3, ks_ = (gj) & 7;                            \
        _Pragma("unroll") for (int g_ = 0; g_ < 4; ++g_)                     \
            dst[g_] = *(const bf16x8*)(Wi2 +                                 \
                (size_t)(((16 * g_ + u_) * 8 + ks_) * 512));                 \
    } while (0)

#define XMFG(b_, gj, u_) do {                                                \
        const int ks_ = (gj) & 7;                                            \
        bf16x8 ah = *(const bf16x8*)&hhi[1][arow * 256 +                     \
                        ((ks_ * 32 + kp * 8) ^ asw)];                        \
        bf16x8 al = *(const bf16x8*)&hlo[1][arow * 256 +                     \
                        ((ks_ * 32 + kp * 8) ^ asw)];                        \
        _Pragma("unroll") for (int g_ = 0; g_ < 4; ++g_) {                   \
            xpf[g_][u_] = BMFMA(al, b_[g_], xpf[g_][u_]);                    \
            xpf[g_][u_] = BMFMA(ah, b_[g_], xpf[g_][u_]);                    \
        }                                                                    \
    } while (0)

    {
        bf16x8 xA[4], xB[4];
        XLOAD(xA, 0); XLOAD(xB, 1);
        XMFG(xA, 0, 0);  XLOAD(xA, 2);
        XMFG(xB, 1, 0);  XLOAD(xB, 3);
        XMFG(xA, 2, 0);  XLOAD(xA, 4);
        XMFG(xB, 3, 0);  XLOAD(xB, 5);
        XMFG(xA, 4, 0);  XLOAD(xA, 6);
        XMFG(xB, 5, 0);  XLOAD(xB, 7);
        XMFG(xA, 6, 0);  XLOAD(xA, 8);
        XMFG(xB, 7, 0);  XLOAD(xB, 9);
        XMFG(xA, 8, 1);  XLOAD(xA, 10);
        XMFG(xB, 9, 1);  XLOAD(xB, 11);
        XMFG(xA, 10, 1); XLOAD(xA, 12);
        XMFG(xB, 11, 1); XLOAD(xB, 13);
        XMFG(xA, 12, 1); XLOAD(xA, 14);
        XMFG(xB, 13, 1); XLOAD(xB, 15);
        XMFG(xA, 14, 1);
        XMFG(xB, 15, 1);
    }
#undef XLOAD
#undef XMFG
    __syncthreads();   // all phi reads done before t=0 overwrites hhi[1]

    // ==================== LSTM main loop (R15 ring) ====================
    const unsigned short* Bh = Wph + (size_t)l * 8;
    char* ra = pool + (w * 3 + 0) * 4096;
    char* rb = pool + (w * 3 + 1) * 4096;
    char* rc = pool + (w * 3 + 2) * 4096;
    const size_t lane16 = (size_t)l * 16;

#define ISSUE(base, gj) do {                                                 \
        const int u_ = (gj) >> 3, ks2_ = (gj) & 7;                           \
        _Pragma("unroll") for (int g_ = 0; g_ < 4; ++g_) {                   \
            const unsigned short* gp_ = Bh +                                 \
                (size_t)(((16 * g_ + 2 * w + u_) * 8 + ks2_) * 64) * 8;      \
            async16(gp_, (base) + g_ * 1024);                                \
        }                                                                    \
    } while (0)

#define CNS(base, gi) do {                                                   \
        asm volatile("s_waitcnt vmcnt(8)" ::: "memory");                     \
        __builtin_amdgcn_sched_barrier(0);                                   \
        const char* p_ = (base) + lane16;                                    \
        bf16x8 f0 = *(const bf16x8*)(p_);                                    \
        bf16x8 f1 = *(const bf16x8*)(p_ + 1024);                             \
        bf16x8 f2 = *(const bf16x8*)(p_ + 2048);                             \
        bf16x8 f3 = *(const bf16x8*)(p_ + 3072);                             \
        const int ks_ = (gi) & 7;                                            \
        bf16x8 ah = *(const bf16x8*)&Ahi[arow * 256 +                        \
                        ((ks_ * 32 + kp * 8) ^ asw)];                        \
        bf16x8 al = *(const bf16x8*)&Alo[arow * 256 +                        \
                        ((ks_ * 32 + kp * 8) ^ asw)];                        \
        acc[0] = BMFMA(al, f0, acc[0]); acc[0] = BMFMA(ah, f0, acc[0]);      \
        acc[1] = BMFMA(al, f1, acc[1]); acc[1] = BMFMA(ah, f1, acc[1]);      \
        acc[2] = BMFMA(al, f2, acc[2]); acc[2] = BMFMA(ah, f2, acc[2]);      \
        acc[3] = BMFMA(al, f3, acc[3]); acc[3] = BMFMA(ah, f3, acc[3]);      \
        asm volatile("" ::: "memory");                                       \
        ISSUE(base, ((gi) + 3) & 15);                                        \
    } while (0)

#define POINTW(u_) do {                                                      \
        float s = 0.0f;                                                      \
        _Pragma("unroll") for (int q = 0; q < 4; ++q) {                      \
            float iv = sigmoidf_(acc[0][q]);                                 \
            float fv = sigmoidf_(acc[1][q]);                                 \
            float gv = tanhf_   (acc[2][q]);                                 \
            float ov = sigmoidf_(acc[3][q]);                                 \
            c[u_][q] = fv * c[u_][q] + iv * gv;                              \
            float hv = ov * tanhf_(c[u_][q]);                                \
            s += hv;                                                         \
            unsigned short h16 = f2bf_rne(hv);                               \
            float lof = hv - bf2f(h16);                                      \
            int row  = kp * 4 + q;                                           \
            int hcol = w * 32 + (u_) * 16 + col;                             \
            int sidx = row * 256 + (hcol ^ ((row & 7) << 3));                \
            Nhi[sidx] = (short)h16;                                          \
            Nlo[sidx] = (short)f2bf_rne(lof);                                \
        }                                                                    \
        su[u_] = s;                                                          \
    } while (0)

    // prologue: 3 groups in flight
    ISSUE(ra, 0); ISSUE(rb, 1); ISSUE(rc, 2);

    float c[2][4];
    #pragma unroll
    for (int u = 0; u < 2; ++u)
        #pragma unroll
        for (int q = 0; q < 4; ++q) c[u][q] = 0.0f;

    for (int t = 0; t < TSTEPS; ++t) {
        const short* Ahi = hhi[t & 1];
        const short* Alo = hlo[t & 1];
        short* Nhi = hhi[(t + 1) & 1];
        short* Nlo = hlo[(t + 1) & 1];

        float su[2];
        f32x4 acc[4];

        // ---- u = 0 ----
        #pragma unroll
        for (int g = 0; g < 4; ++g) acc[g] = xpf[g][0];
        CNS(ra, 0); CNS(rb, 1); CNS(rc, 2); CNS(ra, 3);
        CNS(rb, 4); CNS(rc, 5); CNS(ra, 6); CNS(rb, 7);
        POINTW(0);                       // VALU hides under in-flight loads

        // ---- u = 1 ----
        #pragma unroll
        for (int g = 0; g < 4; ++g) acc[g] = xpf[g][1];
        CNS(rc, 8);  CNS(ra, 9);  CNS(rb, 10); CNS(rc, 11);
        CNS(ra, 12); CNS(rb, 13); CNS(rc, 14); CNS(ra, 15);
        POINTW(1);

        #pragma unroll
        for (int u = 0; u < 2; ++u) {
            float v = su[u];
            v += __shfl_xor(v, 16);
            v += __shfl_xor(v, 32);
            if (l < 16)
                atomicAdd(&esum[t * GH + w * 32 + u * 16 + l], v);
        }

        // raw barrier: flush LDS ops only; keep global_load_lds in flight
        asm volatile("s_waitcnt lgkmcnt(0)" ::: "memory");
        __builtin_amdgcn_s_barrier();
        __builtin_amdgcn_sched_barrier(0);
        asm volatile("" ::: "memory");

        // rotate ring (next step's groups 0,1,2 already landing in rb,rc,ra)
        char* tp = ra; ra = rb; rb = rc; rc = tp;
    }
#undef ISSUE
#undef CNS
#undef POINTW
}

// ---------------------------------------------------------------------------
// Kernel C: proj[t][c] = (esum[t]/4096) @ W1_h + att_b1[c]
// ---------------------------------------------------------------------------
__global__ void proj_kernel(const float* __restrict__ esum,
                            const float* __restrict__ attW1,
                            const float* __restrict__ attb1,
                            float* __restrict__ proj)
{
    __shared__ float part[4][AH];
    const int t   = blockIdx.x;
    const int cix = threadIdx.x & 63;
    const int g   = threadIdx.x >> 6;
    float a = 0.0f;
    #pragma unroll 4
    for (int k = g * 64; k < g * 64 + 64; ++k) {
        float e = esum[t * GH + k] * (1.0f / (float)N_TRAIN);
        a = fmaf(e, attW1[(size_t)(N_TRAIN + k) * AH + cix], a);
    }
    part[g][cix] = a;
    __syncthreads();
    if (threadIdx.x < AH)
        proj[t * AH + cix] = part[0][cix] + part[1][cix] + part[2][cix] +
                             part[3][cix] + attb1[cix];
}

// ---------------------------------------------------------------------------
// Kernel D: S_proj via MFMA (3-term bf16 hi/lo split), fused scores epilogue.
// S prefetch deepened to 4 register buffers (prefetch distance 4 bodies
// ~800-1000 cyc) to cover ~900-cyc HBM latency; statically indexed.
// ---------------------------------------------------------------------------
__global__ __launch_bounds__(512, 4) void scores_kernel(
    const float* __restrict__ S,
    const unsigned short* __restrict__ Wah,
    const unsigned short* __restrict__ Wal,
    const float* __restrict__ proj,
    const float* __restrict__ attw2,
    const float* __restrict__ attb2,
    float* __restrict__ out)
{
    __shared__ float projl[TSTEPS * AH]; // 8 KB
    __shared__ float w2l[AH];

    const int tid   = threadIdx.x;
    const int wv    = tid >> 6;          // 0..7: ante-tile
    const int l     = tid & 63;
    const int kp    = l >> 4;            // 0..3
    const int atile = blockIdx.x * 128 + wv * 16;
    const int an    = atile + (l & 15);  // this lane's A-row (ante)

    f32x4 acc[4];
    #pragma unroll
    for (int ct = 0; ct < 4; ++ct) acc[ct] = (f32x4){0.f, 0.f, 0.f, 0.f};

    const float* Sp = S + an;
    const unsigned short* Bh = Wah + (size_t)l * 8;
    const unsigned short* Bl = Wal + (size_t)l * 8;

#define LOADS(dst, ks_) do {                                                 \
        _Pragma("unroll") for (int jj = 0; jj < 8; ++jj)                     \
            dst[jj] = Sp[(size_t)(32 * (ks_) + kp * 8 + jj) * NANTES];       \
    } while (0)

#define BODY(src, ks_) do {                                                  \
        bf16x8 bh[4], bl[4];                                                 \
        _Pragma("unroll") for (int ct = 0; ct < 4; ++ct) {                   \
            size_t off = (size_t)((ct * 128 + (ks_)) * 64) * 8;              \
            bh[ct] = *(const bf16x8*)(Bh + off);                             \
            bl[ct] = *(const bf16x8*)(Bl + off);                             \
        }                                                                    \
        bf16x8 ah, al;                                                       \
        _Pragma("unroll") for (int jj = 0; jj < 8; ++jj) {                   \
            float x = src[jj];                                               \
            unsigned short h16 = f2bf_rne(x);                                \
            ah[jj] = (short)h16;                                             \
            al[jj] = (short)f2bf_rne(x - bf2f(h16));                         \
        }                                                                    \
        _Pragma("unroll") for (int ct = 0; ct < 4; ++ct) {                   \
            acc[ct] = BMFMA(al, bh[ct], acc[ct]);                            \
            acc[ct] = BMFMA(ah, bl[ct], acc[ct]);                            \
            acc[ct] = BMFMA(ah, bh[ct], acc[ct]);                            \
        }                                                                    \
    } while (0)

    float s0[8], s1[8], s2[8], s3[8];
    LOADS(s0, 0); LOADS(s1, 1); LOADS(s2, 2); LOADS(s3, 3);

    #pragma unroll 1
    for (int ks = 0; ks < 128; ks += 4) {
        BODY(s0, ks + 0); if (ks < 124) LOADS(s0, ks + 4);
        BODY(s1, ks + 1); if (ks < 124) LOADS(s1, ks + 5);
        BODY(s2, ks + 2); if (ks < 124) LOADS(s2, ks + 6);
        BODY(s3, ks + 3); if (ks < 124) LOADS(s3, ks + 7);
    }
#undef LOADS
#undef BODY

    // ---- epilogue ----
    for (int i = tid; i < TSTEPS * AH; i += 512) projl[i] = proj[i];
    if (tid < AH) w2l[tid] = attw2[tid];
    __syncthreads();

    const float b2v = attb2[0];
    const int cn = l & 15;               // C col within tile
    #pragma unroll 1
    for (int t = 0; t < TSTEPS; ++t) {
        #pragma unroll
        for (int q = 0; q < 4; ++q) {
            float sc = 0.0f;
            #pragma unroll
            for (int ct = 0; ct < 4; ++ct) {
                int colg = ct * 16 + cn;
                sc += fmaxf(acc[ct][q] + projl[t * AH + colg], 0.0f) * w2l[colg];
            }
            sc += __shfl_xor(sc, 1);
            sc += __shfl_xor(sc, 2);
            sc += __shfl_xor(sc, 4);
            sc += __shfl_xor(sc, 8);
            if (cn == 0)
                out[(size_t)t * NANTES + atile + kp * 4 + q] = sc + b2v;
        }
    }
}

// ---------------------------------------------------------------------------
// Kernel E: per-step argmax (first-max semantics).
// ---------------------------------------------------------------------------
__global__ void argmax_kernel(const float* __restrict__ scores,
                              float* __restrict__ out)
{
    __shared__ float bv[256];
    __shared__ int   bidx[256];
    const int t = blockIdx.x, tid = threadIdx.x;
    float best = -INFINITY;
    int   bi   = 0x7fffffff;
    for (int a = tid; a < NANTES; a += 256) {
        float v = scores[(size_t)t * NANTES + a];
        if (v > best) { best = v; bi = a; }
    }
    bv[tid] = best; bidx[tid] = bi;
    __syncthreads();
    for (int s = 128; s > 0; s >>= 1) {
        if (tid < s) {
            if (bv[tid + s] > bv[tid] ||
                (bv[tid + s] == bv[tid] && bidx[tid + s] < bidx[tid])) {
                bv[tid] = bv[tid + s];
                bidx[tid] = bidx[tid + s];
            }
        }
        __syncthreads();
    }
    if (tid == 0)
        out[(size_t)TSTEPS * NANTES + t] = (float)bidx[0];
}

// ---------------------------------------------------------------------------
extern "C" void kernel_launch(void* const* d_in, const int* in_sizes, int n_in,
                              void* d_out, int out_size, void* d_ws, size_t ws_size,
                              hipStream_t stream)
{
    const float* ctx   = (const float*)d_in[0];
    const float* S     = (const float*)d_in[1];
    const float* encW1 = (const float*)d_in[2];
    const float* encb1 = (const float*)d_in[3];
    const float* encW2 = (const float*)d_in[4];
    const float* encb2 = (const float*)d_in[5];
    const float* Wih   = (const float*)d_in[6];
    const float* Whh   = (const float*)d_in[7];
    const float* bih   = (const float*)d_in[8];
    const float* bhh   = (const float*)d_in[9];
    const float* attW1 = (const float*)d_in[10];
    const float* attb1 = (const float*)d_in[11];
    const float* attw2 = (const float*)d_in[12];
    const float* attb2 = (const float*)d_in[13];

    char* ws = (char*)d_ws;
    float* esum = (float*)ws;                                      // 32 KB
    float* proj = (float*)(ws + 32768);                            // 8 KB
    unsigned short* Wph = (unsigned short*)(ws + 40960);           // 512 KB
    unsigned short* Wah = (unsigned short*)(ws + 40960 + 524288);  // 512 KB
    unsigned short* Wal = (unsigned short*)(ws + 40960 + 1048576); // 512 KB
    unsigned short* Wpi = (unsigned short*)(ws + 40960 + 1572864); // 512 KB
    float* out  = (float*)d_out;

    prep_kernel<<<dim3(128), dim3(256), 0, stream>>>(
        Whh, Wph, Wih, Wpi, attW1, Wah, Wal, esum);
    lstm_kernel<<<dim3(N_TRAIN / 16), dim3(512), 0, stream>>>(
        ctx, encW1, encb1, encW2, encb2, bih, bhh, Wph, Wpi, esum);
    proj_kernel<<<dim3(TSTEPS), dim3(256), 0, stream>>>(esum, attW1, attb1, proj);
    scores_kernel<<<dim3(NANTES / 128), dim3(512), 0, stream>>>(
        S, Wah, Wal, proj, attw2, attb2, out);
    argmax_kernel<<<dim3(TSTEPS), dim3(256), 0, stream>>>(out, out);
}

// Round 20
// 506.351 us; speedup vs baseline: 1.0392x; 1.0392x over previous
//
#include <hip/hip_runtime.h>
#include <hip/hip_bf16.h>
#include <math.h>

// Problem constants
#define N_TRAIN 4096
#define N_FEAT  64
#define NHID    256
#define ENC     256
#define GH      256
#define AH      64
#define NANTES  32768
#define TSTEPS  32

#define SSTR 528   // lstm setup LDS row stride (f32)

typedef __attribute__((ext_vector_type(8))) short bf16x8;
typedef __attribute__((ext_vector_type(4))) float f32x4;

#define BMFMA(a_, b_, c_) __builtin_amdgcn_mfma_f32_16x16x32_bf16(a_, b_, c_, 0, 0, 0)

__device__ __forceinline__ float sigmoidf_(float x) {
    return 1.0f / (1.0f + __expf(-x));
}
__device__ __forceinline__ float tanhf_(float x) {
    return 1.0f - 2.0f / (__expf(2.0f * x) + 1.0f);
}
__device__ __forceinline__ unsigned short f2bf_rne(float x) {
    unsigned int u = __float_as_uint(x);
    unsigned int r = u + 0x7FFFu + ((u >> 16) & 1u);
    return (unsigned short)(r >> 16);
}
__device__ __forceinline__ float bf2f(unsigned short b) {
    return __uint_as_float(((unsigned int)b) << 16);
}

// async 16B/lane global -> LDS (wave-uniform LDS base, per-lane global src)
__device__ __forceinline__ void async16(const void* g, void* l) {
    __builtin_amdgcn_global_load_lds(
        (const __attribute__((address_space(1))) void*)g,
        (__attribute__((address_space(3))) void*)l, 16, 0, 0);
}

// ---------------------------------------------------------------------------
// Kernel PREP (fused): zero esum + pack Whh and Wih (bf16 hi, fragment
// order; both are [1024][256] row-major) + pack attW1[:4096] (bf16 hi/lo,
// B-fragment order). Grid 128 x 256.
// ---------------------------------------------------------------------------
__global__ void prep_kernel(const float* __restrict__ Whh,
                            unsigned short* __restrict__ Wph,
                            const float* __restrict__ Wih,
                            unsigned short* __restrict__ Wpi,
                            const float* __restrict__ attW1,
                            unsigned short* __restrict__ Wah,
                            unsigned short* __restrict__ Wal,
                            float* __restrict__ esum)
{
    int g = blockIdx.x * 256 + threadIdx.x;      // 0 .. 32767
    if (g < TSTEPS * GH) esum[g] = 0.0f;

    {   // pack Whh + Wih: group g = ((ntile*8 + ks)*64 + lane)
        int lane  = g & 63;
        int ks    = (g >> 6) & 7;
        int ntile = g >> 9;
        int n  = ntile * 16 + (lane & 15);
        int k0 = ks * 32 + (lane >> 4) * 8;
        const float* src1 = Whh + n * 256 + k0;
        const float* src2 = Wih + n * 256 + k0;
        #pragma unroll
        for (int jj = 0; jj < 8; ++jj) {
            Wph[g * 8 + jj] = f2bf_rne(src1[jj]);
            Wpi[g * 8 + jj] = f2bf_rne(src2[jj]);
        }
    }
    {   // pack_wa: group g = ((ct*128 + ks)*64 + lane)
        int lane = g & 63;
        int ks   = (g >> 6) & 127;
        int ct   = g >> 13;
        int n  = ct * 16 + (lane & 15);
        int k0 = ks * 32 + (lane >> 4) * 8;
        const float* src = attW1 + (size_t)k0 * AH + n;
        #pragma unroll
        for (int jj = 0; jj < 8; ++jj) {
            float x = src[(size_t)jj * AH];
            unsigned short h16 = f2bf_rne(x);
            Wah[g * 8 + jj] = h16;
            Wal[g * 8 + jj] = f2bf_rne(x - bf2f(h16));
        }
    }
}

// ---------------------------------------------------------------------------
// Kernel A: fused encoder -> MFMA x_proj -> 32-step MFMA LSTM -> h sums
// (unchanged from round 18 — best measured configuration)
// ---------------------------------------------------------------------------
__global__ __launch_bounds__(512, 2) void lstm_kernel(
    const float* __restrict__ ctx,
    const float* __restrict__ encW1, const float* __restrict__ encb1,
    const float* __restrict__ encW2, const float* __restrict__ encb2,
    const float* __restrict__ bih,  const float* __restrict__ bhh,
    const unsigned short* __restrict__ Wph,
    const unsigned short* __restrict__ Wpi,
    float* __restrict__ esum)
{
    __shared__ char pool[98304];           // B ring (8 waves x 3 x 4KB); sbuf aliased
    __shared__ short hhi[2][16 * 256];     // 8 KB x2, XOR-swizzled cols
    __shared__ short hlo[2][16 * 256];

    float* sbuf = (float*)pool;            // setup scratch (33792 B <= ring)

    const int tid   = threadIdx.x;
    const int j     = tid & 255;
    const int rh    = tid >> 8;
    const int rbase = rh * 8;
    const int r0    = blockIdx.x * 16;

    const int w    = tid >> 6;        // wave 0..7
    const int l    = tid & 63;
    const int col  = l & 15;          // C col / A row
    const int kp   = l >> 4;          // 0..3
    const int arow = col;
    const int asw  = (arow & 7) << 3; // short-unit XOR swizzle

    // ==================== setup ====================
    {
        float acc[8];
        float b = encb1[j];
        #pragma unroll
        for (int r = 0; r < 8; ++r) acc[r] = b;
        for (int k = 0; k < N_FEAT; ++k) {
            float wv = encW1[k * NHID + j];
            #pragma unroll
            for (int r = 0; r < 8; ++r)
                acc[r] = fmaf(ctx[(r0 + rbase + r) * N_FEAT + k], wv, acc[r]);
        }
        #pragma unroll
        for (int r = 0; r < 8; ++r)
            sbuf[(rbase + r) * SSTR + j] = fmaxf(acc[r], 0.0f);
    }
    __syncthreads();

    // phi = hid @ encW2 + b2 (f32x4 LDS reads), staged hi/lo -> hhi[1]/hlo[1]
    {
        float p[8];
        float b = encb2[j];
        #pragma unroll
        for (int r = 0; r < 8; ++r) p[r] = b;
        for (int k4 = 0; k4 < NHID / 4; ++k4) {
            float w0 = encW2[(k4 * 4 + 0) * ENC + j];
            float w1 = encW2[(k4 * 4 + 1) * ENC + j];
            float w2 = encW2[(k4 * 4 + 2) * ENC + j];
            float w3 = encW2[(k4 * 4 + 3) * ENC + j];
            #pragma unroll
            for (int r = 0; r < 8; ++r) {
                const f32x4 hv = *(const f32x4*)&sbuf[(rbase + r) * SSTR + k4 * 4];
                float v = p[r];
                v = fmaf(hv[0], w0, v);
                v = fmaf(hv[1], w1, v);
                v = fmaf(hv[2], w2, v);
                v = fmaf(hv[3], w3, v);
                p[r] = v;
            }
        }
        #pragma unroll
        for (int r = 0; r < 8; ++r) {
            int row = rbase + r;
            unsigned short h16 = f2bf_rne(p[r]);
            float lof = p[r] - bf2f(h16);
            int sidx = row * 256 + (j ^ ((row & 7) << 3));
            hhi[1][sidx] = (short)h16;
            hlo[1][sidx] = (short)f2bf_rne(lof);
        }
    }
    // zero h buffer 0 (t=0 A-operand)
    for (int i = tid; i < 16 * 256; i += 512) { hhi[0][i] = 0; hlo[0][i] = 0; }
    __syncthreads();   // phi staged + zeros visible to all waves

    // ---- x_proj MFMA prologue: xpf = bias + phi @ Wih^T ----
    f32x4 xpf[4][2];
    #pragma unroll
    for (int g = 0; g < 4; ++g)
        #pragma unroll
        for (int u = 0; u < 2; ++u) {
            int m = g * 256 + w * 32 + u * 16 + col;
            float b = bih[m] + bhh[m];
            xpf[g][u] = (f32x4){b, b, b, b};
        }

    const unsigned short* Wi2 = Wpi + (size_t)l * 8 + (size_t)w * 8192;

#define XLOAD(dst, gj) do {                                                  \
        const int u_ = (gj) >> 3, ks_ = (gj) & 7;                            \
        _Pragma("unroll") for (int g_ = 0; g_ < 4; ++g_)                     \
            dst[g_] = *(const bf16x8*)(Wi2 +                                 \
                (size_t)(((16 * g_ + u_) * 8 + ks_) * 512));                 \
    } while (0)

#define XMFG(b_, gj, u_) do {                                                \
        const int ks_ = (gj) & 7;                                            \
        bf16x8 ah = *(const bf16x8*)&hhi[1][arow * 256 +                     \
                        ((ks_ * 32 + kp * 8) ^ asw)];                        \
        bf16x8 al = *(const bf16x8*)&hlo[1][arow * 256 +                     \
                        ((ks_ * 32 + kp * 8) ^ asw)];                        \
        _Pragma("unroll") for (int g_ = 0; g_ < 4; ++g_) {                   \
            xpf[g_][u_] = BMFMA(al, b_[g_], xpf[g_][u_]);                    \
            xpf[g_][u_] = BMFMA(ah, b_[g_], xpf[g_][u_]);                    \
        }                                                                    \
    } while (0)

    {
        bf16x8 xA[4], xB[4];
        XLOAD(xA, 0); XLOAD(xB, 1);
        XMFG(xA, 0, 0);  XLOAD(xA, 2);
        XMFG(xB, 1, 0);  XLOAD(xB, 3);
        XMFG(xA, 2, 0);  XLOAD(xA, 4);
        XMFG(xB, 3, 0);  XLOAD(xB, 5);
        XMFG(xA, 4, 0);  XLOAD(xA, 6);
        XMFG(xB, 5, 0);  XLOAD(xB, 7);
        XMFG(xA, 6, 0);  XLOAD(xA, 8);
        XMFG(xB, 7, 0);  XLOAD(xB, 9);
        XMFG(xA, 8, 1);  XLOAD(xA, 10);
        XMFG(xB, 9, 1);  XLOAD(xB, 11);
        XMFG(xA, 10, 1); XLOAD(xA, 12);
        XMFG(xB, 11, 1); XLOAD(xB, 13);
        XMFG(xA, 12, 1); XLOAD(xA, 14);
        XMFG(xB, 13, 1); XLOAD(xB, 15);
        XMFG(xA, 14, 1);
        XMFG(xB, 15, 1);
    }
#undef XLOAD
#undef XMFG
    __syncthreads();   // all phi reads done before t=0 overwrites hhi[1]

    // ==================== LSTM main loop (R15 ring) ====================
    const unsigned short* Bh = Wph + (size_t)l * 8;
    char* ra = pool + (w * 3 + 0) * 4096;
    char* rb = pool + (w * 3 + 1) * 4096;
    char* rc = pool + (w * 3 + 2) * 4096;
    const size_t lane16 = (size_t)l * 16;

#define ISSUE(base, gj) do {                                                 \
        const int u_ = (gj) >> 3, ks2_ = (gj) & 7;                           \
        _Pragma("unroll") for (int g_ = 0; g_ < 4; ++g_) {                   \
            const unsigned short* gp_ = Bh +                                 \
                (size_t)(((16 * g_ + 2 * w + u_) * 8 + ks2_) * 64) * 8;      \
            async16(gp_, (base) + g_ * 1024);                                \
        }                                                                    \
    } while (0)

#define CNS(base, gi) do {                                                   \
        asm volatile("s_waitcnt vmcnt(8)" ::: "memory");                     \
        __builtin_amdgcn_sched_barrier(0);                                   \
        const char* p_ = (base) + lane16;                                    \
        bf16x8 f0 = *(const bf16x8*)(p_);                                    \
        bf16x8 f1 = *(const bf16x8*)(p_ + 1024);                             \
        bf16x8 f2 = *(const bf16x8*)(p_ + 2048);                             \
        bf16x8 f3 = *(const bf16x8*)(p_ + 3072);                             \
        const int ks_ = (gi) & 7;                                            \
        bf16x8 ah = *(const bf16x8*)&Ahi[arow * 256 +                        \
                        ((ks_ * 32 + kp * 8) ^ asw)];                        \
        bf16x8 al = *(const bf16x8*)&Alo[arow * 256 +                        \
                        ((ks_ * 32 + kp * 8) ^ asw)];                        \
        acc[0] = BMFMA(al, f0, acc[0]); acc[0] = BMFMA(ah, f0, acc[0]);      \
        acc[1] = BMFMA(al, f1, acc[1]); acc[1] = BMFMA(ah, f1, acc[1]);      \
        acc[2] = BMFMA(al, f2, acc[2]); acc[2] = BMFMA(ah, f2, acc[2]);      \
        acc[3] = BMFMA(al, f3, acc[3]); acc[3] = BMFMA(ah, f3, acc[3]);      \
        asm volatile("" ::: "memory");                                       \
        ISSUE(base, ((gi) + 3) & 15);                                        \
    } while (0)

#define POINTW(u_) do {                                                      \
        float s = 0.0f;                                                      \
        _Pragma("unroll") for (int q = 0; q < 4; ++q) {                      \
            float iv = sigmoidf_(acc[0][q]);                                 \
            float fv = sigmoidf_(acc[1][q]);                                 \
            float gv = tanhf_   (acc[2][q]);                                 \
            float ov = sigmoidf_(acc[3][q]);                                 \
            c[u_][q] = fv * c[u_][q] + iv * gv;                              \
            float hv = ov * tanhf_(c[u_][q]);                                \
            s += hv;                                                         \
            unsigned short h16 = f2bf_rne(hv);                               \
            float lof = hv - bf2f(h16);                                      \
            int row  = kp * 4 + q;                                           \
            int hcol = w * 32 + (u_) * 16 + col;                             \
            int sidx = row * 256 + (hcol ^ ((row & 7) << 3));                \
            Nhi[sidx] = (short)h16;                                          \
            Nlo[sidx] = (short)f2bf_rne(lof);                                \
        }                                                                    \
        su[u_] = s;                                                          \
    } while (0)

    // prologue: 3 groups in flight
    ISSUE(ra, 0); ISSUE(rb, 1); ISSUE(rc, 2);

    float c[2][4];
    #pragma unroll
    for (int u = 0; u < 2; ++u)
        #pragma unroll
        for (int q = 0; q < 4; ++q) c[u][q] = 0.0f;

    for (int t = 0; t < TSTEPS; ++t) {
        const short* Ahi = hhi[t & 1];
        const short* Alo = hlo[t & 1];
        short* Nhi = hhi[(t + 1) & 1];
        short* Nlo = hlo[(t + 1) & 1];

        float su[2];
        f32x4 acc[4];

        // ---- u = 0 ----
        #pragma unroll
        for (int g = 0; g < 4; ++g) acc[g] = xpf[g][0];
        CNS(ra, 0); CNS(rb, 1); CNS(rc, 2); CNS(ra, 3);
        CNS(rb, 4); CNS(rc, 5); CNS(ra, 6); CNS(rb, 7);
        POINTW(0);                       // VALU hides under in-flight loads

        // ---- u = 1 ----
        #pragma unroll
        for (int g = 0; g < 4; ++g) acc[g] = xpf[g][1];
        CNS(rc, 8);  CNS(ra, 9);  CNS(rb, 10); CNS(rc, 11);
        CNS(ra, 12); CNS(rb, 13); CNS(rc, 14); CNS(ra, 15);
        POINTW(1);

        #pragma unroll
        for (int u = 0; u < 2; ++u) {
            float v = su[u];
            v += __shfl_xor(v, 16);
            v += __shfl_xor(v, 32);
            if (l < 16)
                atomicAdd(&esum[t * GH + w * 32 + u * 16 + l], v);
        }

        // raw barrier: flush LDS ops only; keep global_load_lds in flight
        asm volatile("s_waitcnt lgkmcnt(0)" ::: "memory");
        __builtin_amdgcn_s_barrier();
        __builtin_amdgcn_sched_barrier(0);
        asm volatile("" ::: "memory");

        // rotate ring (next step's groups 0,1,2 already landing in rb,rc,ra)
        char* tp = ra; ra = rb; rb = rc; rc = tp;
    }
#undef ISSUE
#undef CNS
#undef POINTW
}

// ---------------------------------------------------------------------------
// Kernel C: proj[t][c] = (esum[t]/4096) @ W1_h + att_b1[c]
// ---------------------------------------------------------------------------
__global__ void proj_kernel(const float* __restrict__ esum,
                            const float* __restrict__ attW1,
                            const float* __restrict__ attb1,
                            float* __restrict__ proj)
{
    __shared__ float part[4][AH];
    const int t   = blockIdx.x;
    const int cix = threadIdx.x & 63;
    const int g   = threadIdx.x >> 6;
    float a = 0.0f;
    #pragma unroll 4
    for (int k = g * 64; k < g * 64 + 64; ++k) {
        float e = esum[t * GH + k] * (1.0f / (float)N_TRAIN);
        a = fmaf(e, attW1[(size_t)(N_TRAIN + k) * AH + cix], a);
    }
    part[g][cix] = a;
    __syncthreads();
    if (threadIdx.x < AH)
        proj[t * AH + cix] = part[0][cix] + part[1][cix] + part[2][cix] +
                             part[3][cix] + attb1[cix];
}

// ---------------------------------------------------------------------------
// Kernel D: S_proj via MFMA (3-term bf16 hi/lo split), fused scores epilogue.
// (exact round-18 two-buffer version — best measured)
// ---------------------------------------------------------------------------
__global__ __launch_bounds__(512, 4) void scores_kernel(
    const float* __restrict__ S,
    const unsigned short* __restrict__ Wah,
    const unsigned short* __restrict__ Wal,
    const float* __restrict__ proj,
    const float* __restrict__ attw2,
    const float* __restrict__ attb2,
    float* __restrict__ out)
{
    __shared__ float projl[TSTEPS * AH]; // 8 KB
    __shared__ float w2l[AH];

    const int tid   = threadIdx.x;
    const int wv    = tid >> 6;          // 0..7: ante-tile
    const int l     = tid & 63;
    const int kp    = l >> 4;            // 0..3
    const int atile = blockIdx.x * 128 + wv * 16;
    const int an    = atile + (l & 15);  // this lane's A-row (ante)

    f32x4 acc[4];
    #pragma unroll
    for (int ct = 0; ct < 4; ++ct) acc[ct] = (f32x4){0.f, 0.f, 0.f, 0.f};

    const float* Sp = S + an;
    const unsigned short* Bh = Wah + (size_t)l * 8;
    const unsigned short* Bl = Wal + (size_t)l * 8;

#define LOADS(dst, ks_) do {                                                 \
        _Pragma("unroll") for (int jj = 0; jj < 8; ++jj)                     \
            dst[jj] = Sp[(size_t)(32 * (ks_) + kp * 8 + jj) * NANTES];       \
    } while (0)

    float sA[8], sB[8];
    LOADS(sA, 0);
    LOADS(sB, 1);

    #pragma unroll 2
    for (int ks = 0; ks < 128; ++ks) {
        bf16x8 bh[4], bl[4];
        #pragma unroll
        for (int ct = 0; ct < 4; ++ct) {
            size_t off = (size_t)((ct * 128 + ks) * 64) * 8;
            bh[ct] = *(const bf16x8*)(Bh + off);
            bl[ct] = *(const bf16x8*)(Bl + off);
        }

        float* cur = (ks & 1) ? sB : sA;
        bf16x8 ah, al;
        #pragma unroll
        for (int jj = 0; jj < 8; ++jj) {
            float x = cur[jj];
            unsigned short h16 = f2bf_rne(x);
            ah[jj] = (short)h16;
            al[jj] = (short)f2bf_rne(x - bf2f(h16));
        }

        if (ks < 126) LOADS(cur, ks + 2);

        #pragma unroll
        for (int ct = 0; ct < 4; ++ct) {
            acc[ct] = BMFMA(al, bh[ct], acc[ct]);
            acc[ct] = BMFMA(ah, bl[ct], acc[ct]);
            acc[ct] = BMFMA(ah, bh[ct], acc[ct]);
        }
    }
#undef LOADS

    // ---- epilogue ----
    for (int i = tid; i < TSTEPS * AH; i += 512) projl[i] = proj[i];
    if (tid < AH) w2l[tid] = attw2[tid];
    __syncthreads();

    const float b2v = attb2[0];
    const int cn = l & 15;               // C col within tile
    #pragma unroll 1
    for (int t = 0; t < TSTEPS; ++t) {
        #pragma unroll
        for (int q = 0; q < 4; ++q) {
            float sc = 0.0f;
            #pragma unroll
            for (int ct = 0; ct < 4; ++ct) {
                int colg = ct * 16 + cn;
                sc += fmaxf(acc[ct][q] + projl[t * AH + colg], 0.0f) * w2l[colg];
            }
            sc += __shfl_xor(sc, 1);
            sc += __shfl_xor(sc, 2);
            sc += __shfl_xor(sc, 4);
            sc += __shfl_xor(sc, 8);
            if (cn == 0)
                out[(size_t)t * NANTES + atile + kp * 4 + q] = sc + b2v;
        }
    }
}

// ---------------------------------------------------------------------------
// Kernel E: per-step argmax (first-max semantics).
// ---------------------------------------------------------------------------
__global__ void argmax_kernel(const float* __restrict__ scores,
                              float* __restrict__ out)
{
    __shared__ float bv[256];
    __shared__ int   bidx[256];
    const int t = blockIdx.x, tid = threadIdx.x;
    float best = -INFINITY;
    int   bi   = 0x7fffffff;
    for (int a = tid; a < NANTES; a += 256) {
        float v = scores[(size_t)t * NANTES + a];
        if (v > best) { best = v; bi = a; }
    }
    bv[tid] = best; bidx[tid] = bi;
    __syncthreads();
    for (int s = 128; s > 0; s >>= 1) {
        if (tid < s) {
            if (bv[tid + s] > bv[tid] ||
                (bv[tid + s] == bv[tid] && bidx[tid + s] < bidx[tid])) {
                bv[tid] = bv[tid + s];
                bidx[tid] = bidx[tid + s];
            }
        }
        __syncthreads();
    }
    if (tid == 0)
        out[(size_t)TSTEPS * NANTES + t] = (float)bidx[0];
}

// ---------------------------------------------------------------------------
extern "C" void kernel_launch(void* const* d_in, const int* in_sizes, int n_in,
                              void* d_out, int out_size, void* d_ws, size_t ws_size,
                              hipStream_t stream)
{
    const float* ctx   = (const float*)d_in[0];
    const float* S     = (const float*)d_in[1];
    const float* encW1 = (const float*)d_in[2];
    const float* encb1 = (const float*)d_in[3];
    const float* encW2 = (const float*)d_in[4];
    const float* encb2 = (const float*)d_in[5];
    const float* Wih   = (const float*)d_in[6];
    const float* Whh   = (const float*)d_in[7];
    const float* bih   = (const float*)d_in[8];
    const float* bhh   = (const float*)d_in[9];
    const float* attW1 = (const float*)d_in[10];
    const float* attb1 = (const float*)d_in[11];
    const float* attw2 = (const float*)d_in[12];
    const float* attb2 = (const float*)d_in[13];

    char* ws = (char*)d_ws;
    float* esum = (float*)ws;                                      // 32 KB
    float* proj = (float*)(ws + 32768);                            // 8 KB
    unsigned short* Wph = (unsigned short*)(ws + 40960);           // 512 KB
    unsigned short* Wah = (unsigned short*)(ws + 40960 + 524288);  // 512 KB
    unsigned short* Wal = (unsigned short*)(ws + 40960 + 1048576); // 512 KB
    unsigned short* Wpi = (unsigned short*)(ws + 40960 + 1572864); // 512 KB
    float* out  = (float*)d_out;

    prep_kernel<<<dim3(128), dim3(256), 0, stream>>>(
        Whh, Wph, Wih, Wpi, attW1, Wah, Wal, esum);
    lstm_kernel<<<dim3(N_TRAIN / 16), dim3(512), 0, stream>>>(
        ctx, encW1, encb1, encW2, encb2, bih, bhh, Wph, Wpi, esum);
    proj_kernel<<<dim3(TSTEPS), dim3(256), 0, stream>>>(esum, attW1, attb1, proj);
    scores_kernel<<<dim3(NANTES / 128), dim3(512), 0, stream>>>(
        S, Wah, Wal, proj, attw2, attb2, out);
    argmax_kernel<<<dim3(TSTEPS), dim3(256), 0, stream>>>(out, out);
}

// Round 21
// 501.160 us; speedup vs baseline: 1.0500x; 1.0104x over previous
//
#include <hip/hip_runtime.h>
#include <hip/hip_bf16.h>
#include <math.h>

// Problem constants
#define N_TRAIN 4096
#define N_FEAT  64
#define NHID    256
#define ENC     256
#define GH      256
#define AH      64
#define NANTES  32768
#define TSTEPS  32

#define SSTR 528   // lstm setup LDS row stride (f32)

typedef __attribute__((ext_vector_type(8))) short bf16x8;
typedef __attribute__((ext_vector_type(4))) float f32x4;

#define BMFMA(a_, b_, c_) __builtin_amdgcn_mfma_f32_16x16x32_bf16(a_, b_, c_, 0, 0, 0)

__device__ __forceinline__ float sigmoidf_(float x) {
    return 1.0f / (1.0f + __expf(-x));
}
__device__ __forceinline__ float tanhf_(float x) {
    return 1.0f - 2.0f / (__expf(2.0f * x) + 1.0f);
}
__device__ __forceinline__ unsigned short f2bf_rne(float x) {
    unsigned int u = __float_as_uint(x);
    unsigned int r = u + 0x7FFFu + ((u >> 16) & 1u);
    return (unsigned short)(r >> 16);
}
__device__ __forceinline__ float bf2f(unsigned short b) {
    return __uint_as_float(((unsigned int)b) << 16);
}

// async 16B/lane global -> LDS (wave-uniform LDS base, per-lane global src)
__device__ __forceinline__ void async16(const void* g, void* l) {
    __builtin_amdgcn_global_load_lds(
        (const __attribute__((address_space(1))) void*)g,
        (__attribute__((address_space(3))) void*)l, 16, 0, 0);
}

// ---------------------------------------------------------------------------
// Kernel PREP (fused): zero esum + pack Whh and Wih (bf16 hi, fragment
// order; both are [1024][256] row-major) + pack attW1[:4096] (bf16 hi/lo,
// B-fragment order). Grid 128 x 256.
// ---------------------------------------------------------------------------
__global__ void prep_kernel(const float* __restrict__ Whh,
                            unsigned short* __restrict__ Wph,
                            const float* __restrict__ Wih,
                            unsigned short* __restrict__ Wpi,
                            const float* __restrict__ attW1,
                            unsigned short* __restrict__ Wah,
                            unsigned short* __restrict__ Wal,
                            float* __restrict__ esum)
{
    int g = blockIdx.x * 256 + threadIdx.x;      // 0 .. 32767
    if (g < TSTEPS * GH) esum[g] = 0.0f;

    {   // pack Whh + Wih: group g = ((ntile*8 + ks)*64 + lane)
        int lane  = g & 63;
        int ks    = (g >> 6) & 7;
        int ntile = g >> 9;
        int n  = ntile * 16 + (lane & 15);
        int k0 = ks * 32 + (lane >> 4) * 8;
        const float* src1 = Whh + n * 256 + k0;
        const float* src2 = Wih + n * 256 + k0;
        #pragma unroll
        for (int jj = 0; jj < 8; ++jj) {
            Wph[g * 8 + jj] = f2bf_rne(src1[jj]);
            Wpi[g * 8 + jj] = f2bf_rne(src2[jj]);
        }
    }
    {   // pack_wa: group g = ((ct*128 + ks)*64 + lane)
        int lane = g & 63;
        int ks   = (g >> 6) & 127;
        int ct   = g >> 13;
        int n  = ct * 16 + (lane & 15);
        int k0 = ks * 32 + (lane >> 4) * 8;
        const float* src = attW1 + (size_t)k0 * AH + n;
        #pragma unroll
        for (int jj = 0; jj < 8; ++jj) {
            float x = src[(size_t)jj * AH];
            unsigned short h16 = f2bf_rne(x);
            Wah[g * 8 + jj] = h16;
            Wal[g * 8 + jj] = f2bf_rne(x - bf2f(h16));
        }
    }
}

// ---------------------------------------------------------------------------
// Kernel A: fused encoder -> MFMA x_proj -> 32-step MFMA LSTM -> h sums
// R18 structure + ONE change: per-step e-sums now land in a per-block LDS
// buffer (plain ds_write; each (t,col) owned by one thread) and are flushed
// to global esum with atomics ONCE after the loop. This removes 2M contended
// global atomics from the hot loop AND keeps them out of the vmcnt queue
// that CNS's counted s_waitcnt vmcnt(8) waits on. LDS = 160 KB exactly.
// ---------------------------------------------------------------------------
__global__ __launch_bounds__(512, 2) void lstm_kernel(
    const float* __restrict__ ctx,
    const float* __restrict__ encW1, const float* __restrict__ encb1,
    const float* __restrict__ encW2, const float* __restrict__ encb2,
    const float* __restrict__ bih,  const float* __restrict__ bhh,
    const unsigned short* __restrict__ Wph,
    const unsigned short* __restrict__ Wpi,
    float* __restrict__ esum)
{
    __shared__ char pool[98304];           // B ring (8 waves x 3 x 4KB); sbuf aliased
    __shared__ short hhi[2][16 * 256];     // 8 KB x2, XOR-swizzled cols
    __shared__ short hlo[2][16 * 256];
    __shared__ float esuml[TSTEPS * GH];   // 32 KB per-block e-sum accumulator

    float* sbuf = (float*)pool;            // setup scratch (33792 B <= ring)

    const int tid   = threadIdx.x;
    const int j     = tid & 255;
    const int rh    = tid >> 8;
    const int rbase = rh * 8;
    const int r0    = blockIdx.x * 16;

    const int w    = tid >> 6;        // wave 0..7
    const int l    = tid & 63;
    const int col  = l & 15;          // C col / A row
    const int kp   = l >> 4;          // 0..3
    const int arow = col;
    const int asw  = (arow & 7) << 3; // short-unit XOR swizzle

    // ==================== setup ====================
    {
        float acc[8];
        float b = encb1[j];
        #pragma unroll
        for (int r = 0; r < 8; ++r) acc[r] = b;
        for (int k = 0; k < N_FEAT; ++k) {
            float wv = encW1[k * NHID + j];
            #pragma unroll
            for (int r = 0; r < 8; ++r)
                acc[r] = fmaf(ctx[(r0 + rbase + r) * N_FEAT + k], wv, acc[r]);
        }
        #pragma unroll
        for (int r = 0; r < 8; ++r)
            sbuf[(rbase + r) * SSTR + j] = fmaxf(acc[r], 0.0f);
    }
    __syncthreads();

    // phi = hid @ encW2 + b2 (f32x4 LDS reads), staged hi/lo -> hhi[1]/hlo[1]
    {
        float p[8];
        float b = encb2[j];
        #pragma unroll
        for (int r = 0; r < 8; ++r) p[r] = b;
        for (int k4 = 0; k4 < NHID / 4; ++k4) {
            float w0 = encW2[(k4 * 4 + 0) * ENC + j];
            float w1 = encW2[(k4 * 4 + 1) * ENC + j];
            float w2 = encW2[(k4 * 4 + 2) * ENC + j];
            float w3 = encW2[(k4 * 4 + 3) * ENC + j];
            #pragma unroll
            for (int r = 0; r < 8; ++r) {
                const f32x4 hv = *(const f32x4*)&sbuf[(rbase + r) * SSTR + k4 * 4];
                float v = p[r];
                v = fmaf(hv[0], w0, v);
                v = fmaf(hv[1], w1, v);
                v = fmaf(hv[2], w2, v);
                v = fmaf(hv[3], w3, v);
                p[r] = v;
            }
        }
        #pragma unroll
        for (int r = 0; r < 8; ++r) {
            int row = rbase + r;
            unsigned short h16 = f2bf_rne(p[r]);
            float lof = p[r] - bf2f(h16);
            int sidx = row * 256 + (j ^ ((row & 7) << 3));
            hhi[1][sidx] = (short)h16;
            hlo[1][sidx] = (short)f2bf_rne(lof);
        }
    }
    // zero h buffer 0 (t=0 A-operand)
    for (int i = tid; i < 16 * 256; i += 512) { hhi[0][i] = 0; hlo[0][i] = 0; }
    __syncthreads();   // phi staged + zeros visible to all waves

    // ---- x_proj MFMA prologue: xpf = bias + phi @ Wih^T ----
    f32x4 xpf[4][2];
    #pragma unroll
    for (int g = 0; g < 4; ++g)
        #pragma unroll
        for (int u = 0; u < 2; ++u) {
            int m = g * 256 + w * 32 + u * 16 + col;
            float b = bih[m] + bhh[m];
            xpf[g][u] = (f32x4){b, b, b, b};
        }

    const unsigned short* Wi2 = Wpi + (size_t)l * 8 + (size_t)w * 8192;

#define XLOAD(dst, gj) do {                                                  \
        const int u_ = (gj) >> 3, ks_ = (gj) & 7;                            \
        _Pragma("unroll") for (int g_ = 0; g_ < 4; ++g_)                     \
            dst[g_] = *(const bf16x8*)(Wi2 +                                 \
                (size_t)(((16 * g_ + u_) * 8 + ks_) * 512));                 \
    } while (0)

#define XMFG(b_, gj, u_) do {                                                \
        const int ks_ = (gj) & 7;                                            \
        bf16x8 ah = *(const bf16x8*)&hhi[1][arow * 256 +                     \
                        ((ks_ * 32 + kp * 8) ^ asw)];                        \
        bf16x8 al = *(const bf16x8*)&hlo[1][arow * 256 +                     \
                        ((ks_ * 32 + kp * 8) ^ asw)];                        \
        _Pragma("unroll") for (int g_ = 0; g_ < 4; ++g_) {                   \
            xpf[g_][u_] = BMFMA(al, b_[g_], xpf[g_][u_]);                    \
            xpf[g_][u_] = BMFMA(ah, b_[g_], xpf[g_][u_]);                    \
        }                                                                    \
    } while (0)

    {
        bf16x8 xA[4], xB[4];
        XLOAD(xA, 0); XLOAD(xB, 1);
        XMFG(xA, 0, 0);  XLOAD(xA, 2);
        XMFG(xB, 1, 0);  XLOAD(xB, 3);
        XMFG(xA, 2, 0);  XLOAD(xA, 4);
        XMFG(xB, 3, 0);  XLOAD(xB, 5);
        XMFG(xA, 4, 0);  XLOAD(xA, 6);
        XMFG(xB, 5, 0);  XLOAD(xB, 7);
        XMFG(xA, 6, 0);  XLOAD(xA, 8);
        XMFG(xB, 7, 0);  XLOAD(xB, 9);
        XMFG(xA, 8, 1);  XLOAD(xA, 10);
        XMFG(xB, 9, 1);  XLOAD(xB, 11);
        XMFG(xA, 10, 1); XLOAD(xA, 12);
        XMFG(xB, 11, 1); XLOAD(xB, 13);
        XMFG(xA, 12, 1); XLOAD(xA, 14);
        XMFG(xB, 13, 1); XLOAD(xB, 15);
        XMFG(xA, 14, 1);
        XMFG(xB, 15, 1);
    }
#undef XLOAD
#undef XMFG
    __syncthreads();   // all phi reads done before t=0 overwrites hhi[1]

    // ==================== LSTM main loop (R15 ring) ====================
    const unsigned short* Bh = Wph + (size_t)l * 8;
    char* ra = pool + (w * 3 + 0) * 4096;
    char* rb = pool + (w * 3 + 1) * 4096;
    char* rc = pool + (w * 3 + 2) * 4096;
    const size_t lane16 = (size_t)l * 16;

#define ISSUE(base, gj) do {                                                 \
        const int u_ = (gj) >> 3, ks2_ = (gj) & 7;                           \
        _Pragma("unroll") for (int g_ = 0; g_ < 4; ++g_) {                   \
            const unsigned short* gp_ = Bh +                                 \
                (size_t)(((16 * g_ + 2 * w + u_) * 8 + ks2_) * 64) * 8;      \
            async16(gp_, (base) + g_ * 1024);                                \
        }                                                                    \
    } while (0)

#define CNS(base, gi) do {                                                   \
        asm volatile("s_waitcnt vmcnt(8)" ::: "memory");                     \
        __builtin_amdgcn_sched_barrier(0);                                   \
        const char* p_ = (base) + lane16;                                    \
        bf16x8 f0 = *(const bf16x8*)(p_);                                    \
        bf16x8 f1 = *(const bf16x8*)(p_ + 1024);                             \
        bf16x8 f2 = *(const bf16x8*)(p_ + 2048);                             \
        bf16x8 f3 = *(const bf16x8*)(p_ + 3072);                             \
        const int ks_ = (gi) & 7;                                            \
        bf16x8 ah = *(const bf16x8*)&Ahi[arow * 256 +                        \
                        ((ks_ * 32 + kp * 8) ^ asw)];                        \
        bf16x8 al = *(const bf16x8*)&Alo[arow * 256 +                        \
                        ((ks_ * 32 + kp * 8) ^ asw)];                        \
        acc[0] = BMFMA(al, f0, acc[0]); acc[0] = BMFMA(ah, f0, acc[0]);      \
        acc[1] = BMFMA(al, f1, acc[1]); acc[1] = BMFMA(ah, f1, acc[1]);      \
        acc[2] = BMFMA(al, f2, acc[2]); acc[2] = BMFMA(ah, f2, acc[2]);      \
        acc[3] = BMFMA(al, f3, acc[3]); acc[3] = BMFMA(ah, f3, acc[3]);      \
        asm volatile("" ::: "memory");                                       \
        ISSUE(base, ((gi) + 3) & 15);                                        \
    } while (0)

#define POINTW(u_) do {                                                      \
        float s = 0.0f;                                                      \
        _Pragma("unroll") for (int q = 0; q < 4; ++q) {                      \
            float iv = sigmoidf_(acc[0][q]);                                 \
            float fv = sigmoidf_(acc[1][q]);                                 \
            float gv = tanhf_   (acc[2][q]);                                 \
            float ov = sigmoidf_(acc[3][q]);                                 \
            c[u_][q] = fv * c[u_][q] + iv * gv;                              \
            float hv = ov * tanhf_(c[u_][q]);                                \
            s += hv;                                                         \
            unsigned short h16 = f2bf_rne(hv);                               \
            float lof = hv - bf2f(h16);                                      \
            int row  = kp * 4 + q;                                           \
            int hcol = w * 32 + (u_) * 16 + col;                             \
            int sidx = row * 256 + (hcol ^ ((row & 7) << 3));                \
            Nhi[sidx] = (short)h16;                                          \
            Nlo[sidx] = (short)f2bf_rne(lof);                                \
        }                                                                    \
        su[u_] = s;                                                          \
    } while (0)

    // prologue: 3 groups in flight
    ISSUE(ra, 0); ISSUE(rb, 1); ISSUE(rc, 2);

    float c[2][4];
    #pragma unroll
    for (int u = 0; u < 2; ++u)
        #pragma unroll
        for (int q = 0; q < 4; ++q) c[u][q] = 0.0f;

    for (int t = 0; t < TSTEPS; ++t) {
        const short* Ahi = hhi[t & 1];
        const short* Alo = hlo[t & 1];
        short* Nhi = hhi[(t + 1) & 1];
        short* Nlo = hlo[(t + 1) & 1];

        float su[2];
        f32x4 acc[4];

        // ---- u = 0 ----
        #pragma unroll
        for (int g = 0; g < 4; ++g) acc[g] = xpf[g][0];
        CNS(ra, 0); CNS(rb, 1); CNS(rc, 2); CNS(ra, 3);
        CNS(rb, 4); CNS(rc, 5); CNS(ra, 6); CNS(rb, 7);
        POINTW(0);                       // VALU hides under in-flight loads

        // ---- u = 1 ----
        #pragma unroll
        for (int g = 0; g < 4; ++g) acc[g] = xpf[g][1];
        CNS(rc, 8);  CNS(ra, 9);  CNS(rb, 10); CNS(rc, 11);
        CNS(ra, 12); CNS(rb, 13); CNS(rc, 14); CNS(ra, 15);
        POINTW(1);

        // e-sum: shfl-reduce over rows, then plain LDS write (one owner
        // per (t,col) per block) — NO global atomics in the hot loop.
        #pragma unroll
        for (int u = 0; u < 2; ++u) {
            float v = su[u];
            v += __shfl_xor(v, 16);
            v += __shfl_xor(v, 32);
            if (l < 16)
                esuml[t * GH + w * 32 + u * 16 + l] = v;
        }

        // raw barrier: flush LDS ops only; keep global_load_lds in flight
        asm volatile("s_waitcnt lgkmcnt(0)" ::: "memory");
        __builtin_amdgcn_s_barrier();
        __builtin_amdgcn_sched_barrier(0);
        asm volatile("" ::: "memory");

        // rotate ring (next step's groups 0,1,2 already landing in rb,rc,ra)
        char* tp = ra; ra = rb; rb = rc; rc = tp;
    }
#undef ISSUE
#undef CNS
#undef POINTW

    // ---- one-time e-sum flush to global (bulk atomics, off critical path)
    __syncthreads();
    for (int i = tid; i < TSTEPS * GH; i += 512)
        atomicAdd(&esum[i], esuml[i]);
}

// ---------------------------------------------------------------------------
// Kernel C: proj[t][c] = (esum[t]/4096) @ W1_h + att_b1[c]
// ---------------------------------------------------------------------------
__global__ void proj_kernel(const float* __restrict__ esum,
                            const float* __restrict__ attW1,
                            const float* __restrict__ attb1,
                            float* __restrict__ proj)
{
    __shared__ float part[4][AH];
    const int t   = blockIdx.x;
    const int cix = threadIdx.x & 63;
    const int g   = threadIdx.x >> 6;
    float a = 0.0f;
    #pragma unroll 4
    for (int k = g * 64; k < g * 64 + 64; ++k) {
        float e = esum[t * GH + k] * (1.0f / (float)N_TRAIN);
        a = fmaf(e, attW1[(size_t)(N_TRAIN + k) * AH + cix], a);
    }
    part[g][cix] = a;
    __syncthreads();
    if (threadIdx.x < AH)
        proj[t * AH + cix] = part[0][cix] + part[1][cix] + part[2][cix] +
                             part[3][cix] + attb1[cix];
}

// ---------------------------------------------------------------------------
// Kernel D: S_proj via MFMA (3-term bf16 hi/lo split), fused scores epilogue.
// (exact round-18 two-buffer version — best measured)
// ---------------------------------------------------------------------------
__global__ __launch_bounds__(512, 4) void scores_kernel(
    const float* __restrict__ S,
    const unsigned short* __restrict__ Wah,
    const unsigned short* __restrict__ Wal,
    const float* __restrict__ proj,
    const float* __restrict__ attw2,
    const float* __restrict__ attb2,
    float* __restrict__ out)
{
    __shared__ float projl[TSTEPS * AH]; // 8 KB
    __shared__ float w2l[AH];

    const int tid   = threadIdx.x;
    const int wv    = tid >> 6;          // 0..7: ante-tile
    const int l     = tid & 63;
    const int kp    = l >> 4;            // 0..3
    const int atile = blockIdx.x * 128 + wv * 16;
    const int an    = atile + (l & 15);  // this lane's A-row (ante)

    f32x4 acc[4];
    #pragma unroll
    for (int ct = 0; ct < 4; ++ct) acc[ct] = (f32x4){0.f, 0.f, 0.f, 0.f};

    const float* Sp = S + an;
    const unsigned short* Bh = Wah + (size_t)l * 8;
    const unsigned short* Bl = Wal + (size_t)l * 8;

#define LOADS(dst, ks_) do {                                                 \
        _Pragma("unroll") for (int jj = 0; jj < 8; ++jj)                     \
            dst[jj] = Sp[(size_t)(32 * (ks_) + kp * 8 + jj) * NANTES];       \
    } while (0)

    float sA[8], sB[8];
    LOADS(sA, 0);
    LOADS(sB, 1);

    #pragma unroll 2
    for (int ks = 0; ks < 128; ++ks) {
        bf16x8 bh[4], bl[4];
        #pragma unroll
        for (int ct = 0; ct < 4; ++ct) {
            size_t off = (size_t)((ct * 128 + ks) * 64) * 8;
            bh[ct] = *(const bf16x8*)(Bh + off);
            bl[ct] = *(const bf16x8*)(Bl + off);
        }

        float* cur = (ks & 1) ? sB : sA;
        bf16x8 ah, al;
        #pragma unroll
        for (int jj = 0; jj < 8; ++jj) {
            float x = cur[jj];
            unsigned short h16 = f2bf_rne(x);
            ah[jj] = (short)h16;
            al[jj] = (short)f2bf_rne(x - bf2f(h16));
        }

        if (ks < 126) LOADS(cur, ks + 2);

        #pragma unroll
        for (int ct = 0; ct < 4; ++ct) {
            acc[ct] = BMFMA(al, bh[ct], acc[ct]);
            acc[ct] = BMFMA(ah, bl[ct], acc[ct]);
            acc[ct] = BMFMA(ah, bh[ct], acc[ct]);
        }
    }
#undef LOADS

    // ---- epilogue ----
    for (int i = tid; i < TSTEPS * AH; i += 512) projl[i] = proj[i];
    if (tid < AH) w2l[tid] = attw2[tid];
    __syncthreads();

    const float b2v = attb2[0];
    const int cn = l & 15;               // C col within tile
    #pragma unroll 1
    for (int t = 0; t < TSTEPS; ++t) {
        #pragma unroll
        for (int q = 0; q < 4; ++q) {
            float sc = 0.0f;
            #pragma unroll
            for (int ct = 0; ct < 4; ++ct) {
                int colg = ct * 16 + cn;
                sc += fmaxf(acc[ct][q] + projl[t * AH + colg], 0.0f) * w2l[colg];
            }
            sc += __shfl_xor(sc, 1);
            sc += __shfl_xor(sc, 2);
            sc += __shfl_xor(sc, 4);
            sc += __shfl_xor(sc, 8);
            if (cn == 0)
                out[(size_t)t * NANTES + atile + kp * 4 + q] = sc + b2v;
        }
    }
}

// ---------------------------------------------------------------------------
// Kernel E: per-step argmax (first-max semantics).
// ---------------------------------------------------------------------------
__global__ void argmax_kernel(const float* __restrict__ scores,
                              float* __restrict__ out)
{
    __shared__ float bv[256];
    __shared__ int   bidx[256];
    const int t = blockIdx.x, tid = threadIdx.x;
    float best = -INFINITY;
    int   bi   = 0x7fffffff;
    for (int a = tid; a < NANTES; a += 256) {
        float v = scores[(size_t)t * NANTES + a];
        if (v > best) { best = v; bi = a; }
    }
    bv[tid] = best; bidx[tid] = bi;
    __syncthreads();
    for (int s = 128; s > 0; s >>= 1) {
        if (tid < s) {
            if (bv[tid + s] > bv[tid] ||
                (bv[tid + s] == bv[tid] && bidx[tid + s] < bidx[tid])) {
                bv[tid] = bv[tid + s];
                bidx[tid] = bidx[tid + s];
            }
        }
        __syncthreads();
    }
    if (tid == 0)
        out[(size_t)TSTEPS * NANTES + t] = (float)bidx[0];
}

// ---------------------------------------------------------------------------
extern "C" void kernel_launch(void* const* d_in, const int* in_sizes, int n_in,
                              void* d_out, int out_size, void* d_ws, size_t ws_size,
                              hipStream_t stream)
{
    const float* ctx   = (const float*)d_in[0];
    const float* S     = (const float*)d_in[1];
    const float* encW1 = (const float*)d_in[2];
    const float* encb1 = (const float*)d_in[3];
    const float* encW2 = (const float*)d_in[4];
    const float* encb2 = (const float*)d_in[5];
    const float* Wih   = (const float*)d_in[6];
    const float* Whh   = (const float*)d_in[7];
    const float* bih   = (const float*)d_in[8];
    const float* bhh   = (const float*)d_in[9];
    const float* attW1 = (const float*)d_in[10];
    const float* attb1 = (const float*)d_in[11];
    const float* attw2 = (const float*)d_in[12];
    const float* attb2 = (const float*)d_in[13];

    char* ws = (char*)d_ws;
    float* esum = (float*)ws;                                      // 32 KB
    float* proj = (float*)(ws + 32768);                            // 8 KB
    unsigned short* Wph = (unsigned short*)(ws + 40960);           // 512 KB
    unsigned short* Wah = (unsigned short*)(ws + 40960 + 524288);  // 512 KB
    unsigned short* Wal = (unsigned short*)(ws + 40960 + 1048576); // 512 KB
    unsigned short* Wpi = (unsigned short*)(ws + 40960 + 1572864); // 512 KB
    float* out  = (float*)d_out;

    prep_kernel<<<dim3(128), dim3(256), 0, stream>>>(
        Whh, Wph, Wih, Wpi, attW1, Wah, Wal, esum);
    lstm_kernel<<<dim3(N_TRAIN / 16), dim3(512), 0, stream>>>(
        ctx, encW1, encb1, encW2, encb2, bih, bhh, Wph, Wpi, esum);
    proj_kernel<<<dim3(TSTEPS), dim3(256), 0, stream>>>(esum, attW1, attb1, proj);
    scores_kernel<<<dim3(NANTES / 128), dim3(512), 0, stream>>>(
        S, Wah, Wal, proj, attw2, attb2, out);
    argmax_kernel<<<dim3(TSTEPS), dim3(256), 0, stream>>>(out, out);
}